// Round 10
// baseline (9773.846 us; speedup 1.0000x reference)
//
#include <hip/hip_runtime.h>

typedef __bf16 bf16;
typedef __bf16 bf16x8 __attribute__((ext_vector_type(8)));
typedef float  f32x16 __attribute__((ext_vector_type(16)));
typedef unsigned short u16;

#define MFMA(a,b,c) __builtin_amdgcn_mfma_f32_32x32x16_bf16((a),(b),(c),0,0,0)

#define BSZ  2048
#define H    256
#define NOUT 5
#define BM   64              // batch rows per block (2 row-groups x 32)
#define NBLK (BSZ/BM)        // 32 blocks, zero inter-block communication

// packed weight fragments (16B each): big mats frag id = (tile*16+ks)*64+lane
// (VERIFIED layout, rounds 1-9)
#define F_WHH1 0
#define F_WIH2 24576
#define F_WHH2 49152
#define F_WIH1 73728
#define F_LIN  75264
#define F_TOTAL 76288

__device__ bf16x8 g_pk[F_TOTAL];

__global__ void prepack_kernel(const float* __restrict__ wih1,
                               const float* __restrict__ whh1,
                               const float* __restrict__ wih2,
                               const float* __restrict__ whh2,
                               const float* __restrict__ lin_w) {
  int fid = blockIdx.x * 256 + threadIdx.x;
  if (fid >= F_TOTAL) return;
  bf16x8 v;
  if (fid < F_WIH1) {
    const float* W = (fid < F_WIH2) ? whh1 : (fid < F_WHH2) ? wih2 : whh2;
    int r    = fid % 24576;
    int tile = r >> 10;
    int ks   = (r >> 6) & 15;
    int lane = r & 63;
    int n = tile * 32 + (lane & 31);
    int k = ks * 16 + (lane >> 5) * 8;
    const float* p = W + n * 256 + k;
#pragma unroll
    for (int i = 0; i < 8; ++i) v[i] = (bf16)p[i];
  } else if (fid < F_LIN) {
    int r    = fid - F_WIH1;
    int tile = r >> 6;
    int lane = r & 63;
    int n  = tile * 32 + (lane & 31);
    int k0 = (lane >> 5) * 8;
#pragma unroll
    for (int i = 0; i < 8; ++i) {
      int kk = k0 + i;
      v[i] = (kk < 8) ? (bf16)wih1[n * 8 + kk] : (bf16)0.f;
    }
  } else {
    int r    = fid - F_LIN;
    int ks   = r >> 6;
    int lane = r & 63;
    int n = lane & 31;
    int k = ks * 16 + (lane >> 5) * 8;
#pragma unroll
    for (int i = 0; i < 8; ++i)
      v[i] = (n < NOUT) ? (bf16)lin_w[n * 256 + k + i] : (bf16)0.f;
  }
  g_pk[fid] = v;
}

__device__ __forceinline__ float sigmoidf_(float x) { return 1.f / (1.f + __expf(-x)); }
__device__ __forceinline__ float tanhf_(float x) {
  float e = __expf(-2.f * x);
  return (1.f - e) / (1.f + e);
}
__device__ __forceinline__ u16 bfb(float x) { bf16 b = (bf16)x; return *(u16*)&b; }

// Zero-sync batch-split GRU. One 1024-thread block per CU (LDS 130KB forces
// 1 block/CU), BM=64: 16 waves = 4/SIMD (r1's proven TLP) issuing ONE
// block-synchronized weight stream: wave (wr,wc) computes rows [32wr,32wr+32)
// x gate tiles {wc, wc+8, wc+16}; the wr=0/wr=1 wave pair reads identical
// B-frags in the same barrier epoch -> second read L1-hits instead of
// doubling L2 return traffic (r1 paid 2x via two unsynchronized blocks).
// Rolled ks loops (I$ discipline, r9 lesson). 3 barriers/step, no inter-block
// sync of any kind.
__global__ __launch_bounds__(1024) void gru_kernel(
    const int* __restrict__ plen_p,
    const float* __restrict__ rnn_in,
    const float* __restrict__ out0,
    const float* __restrict__ h01,
    const float* __restrict__ h02,
    const float* __restrict__ bih1, const float* __restrict__ bhh1,
    const float* __restrict__ bih2, const float* __restrict__ bhh2,
    const float* __restrict__ lin_b,
    float* __restrict__ out) {
  __shared__ u16 h1s[2][BM * 256];     // 32KB each, swizzled, double-buffered
  __shared__ u16 h2s[2][BM * 256];
  __shared__ u16 xs[BM * 16];          // [out(5), u(3), zeros(8)]

  const int T   = plen_p[0];
  const int tid = threadIdx.x;
  const int w   = tid >> 6;            // 0..15
  const int wc  = w & 7;               // gate-tile column wave
  const int wr  = w >> 3;              // row group (0: rows 0-31, 1: rows 32-63)
  const int l   = tid & 63;
  const int col = l & 31;
  const int hv  = l >> 5;
  const int b0  = blockIdx.x * BM;
  const int rb  = wr * 32;             // row base
  const int jd  = wc * 32 + col;       // this lane's h-dim / gate column
  const int am  = rb + col;            // A-fragment row for this lane

  // ---- per-lane biases ----
  float br1 = bih1[jd] + bhh1[jd];
  float bz1 = bih1[H + jd] + bhh1[H + jd];
  float bi1 = bih1[2 * H + jd];
  float bh1 = bhh1[2 * H + jd];
  float br2 = bih2[jd] + bhh2[jd];
  float bz2 = bih2[H + jd] + bhh2[H + jd];
  float bi2 = bih2[2 * H + jd];
  float bh2 = bhh2[2 * H + jd];
  float lb  = (col < NOUT) ? lin_b[col] : 0.f;

  // ---- fp32 master h state in C/D layout: reg q -> row rb+(q&3)+8*(q>>2)+4*hv
  float h1r[16], h2r[16];
#pragma unroll
  for (int q = 0; q < 16; ++q) {
    int m  = rb + (q & 3) + 8 * (q >> 2) + 4 * hv;
    h1r[q] = h01[(size_t)(b0 + m) * H + jd];
    h2r[q] = h02[(size_t)(b0 + m) * H + jd];
  }

  // ---- LDS init: bf16 shadows (swizzled on 16B units within 32-row stripes)
  for (int idx = tid; idx < BM * 32; idx += 1024) {
    int m = idx >> 5, u8 = idx & 31;
    const float* p1 = h01 + (size_t)(b0 + m) * H + u8 * 8;
    const float* p2 = h02 + (size_t)(b0 + m) * H + u8 * 8;
    bf16x8 v1, v2;
#pragma unroll
    for (int i = 0; i < 8; ++i) { v1[i] = (bf16)p1[i]; v2[i] = (bf16)p2[i]; }
    int off = (m << 8) + ((u8 ^ (m & 31)) << 3);
    *(bf16x8*)&h1s[0][off] = v1;
    *(bf16x8*)&h2s[0][off] = v2;
  }
  if (tid < 512) { int m = tid >> 3, c = 8 + (tid & 7); xs[m * 16 + c] = 0; }
  if (tid < 320) { int m = tid / 5, o = tid % 5; xs[m * 16 + o] = bfb(out0[(size_t)(b0 + m) * NOUT + o]); }
  if (tid >= 512 && tid < 704) {
    int r = tid - 512; int m = r / 3, c = r % 3;
    xs[m * 16 + 5 + c] = bfb(rnn_in[(size_t)(b0 + m) * 4 + c]);
  }
  __syncthreads();

  int cur = 0;

  for (int t = 0; t < T; ++t) {
    const u16* h1c = h1s[cur];
    const u16* h2c = h2s[cur];
    u16* h1n = h1s[cur ^ 1];
    u16* h2n = h2s[cur ^ 1];

    // u(t+1) prefetch: wave 1, lane l owns row l (held in regs until bar3)
    float ux = 0.f, uy = 0.f, uz = 0.f;
    if (w == 1 && t + 1 < T) {
      const float4 uu = *(const float4*)&rnn_in[((size_t)(t + 1) * BSZ + b0 + l) * 4];
      ux = uu.x; uy = uu.y; uz = uu.z;
    }

    // ================= layer 1 =================
    f32x16 ar, az, ahn, ain;
#pragma unroll
    for (int i = 0; i < 16; ++i) { ar[i] = 0.f; az[i] = 0.f; ahn[i] = 0.f; ain[i] = 0.f; }
    {
      const bf16x8* pr = g_pk + F_WHH1 + (wc     ) * 1024 + l;
      const bf16x8* pz = g_pk + F_WHH1 + (wc +  8) * 1024 + l;
      const bf16x8* pn = g_pk + F_WHH1 + (wc + 16) * 1024 + l;
#pragma unroll 4
      for (int ks = 0; ks < 16; ++ks) {
        bf16x8 a = *(const bf16x8*)&h1c[am * 256 + (((2 * ks + hv) ^ (am & 31)) << 3)];
        ar  = MFMA(a, pr[ks * 64], ar);
        az  = MFMA(a, pz[ks * 64], az);
        ahn = MFMA(a, pn[ks * 64], ahn);
      }
      bf16x8 ax = *(const bf16x8*)&xs[am * 16 + hv * 8];
      ar  = MFMA(ax, g_pk[F_WIH1 + (wc     ) * 64 + l], ar);
      az  = MFMA(ax, g_pk[F_WIH1 + (wc +  8) * 64 + l], az);
      ain = MFMA(ax, g_pk[F_WIH1 + (wc + 16) * 64 + l], ain);
    }
#pragma unroll
    for (int q = 0; q < 16; ++q) {
      float r = sigmoidf_(ar[q] + br1);
      float z = sigmoidf_(az[q] + bz1);
      float n = tanhf_(ain[q] + bi1 + r * (ahn[q] + bh1));
      float h = (1.f - z) * n + z * h1r[q];
      h1r[q]  = h;
      int m = rb + (q & 3) + 8 * (q >> 2) + 4 * hv;
      h1n[m * 256 + (((jd >> 3) ^ (m & 31)) << 3) + (jd & 7)] = bfb(h);
    }
    __syncthreads();

    // ================= layer 2 =================
#pragma unroll
    for (int i = 0; i < 16; ++i) { ar[i] = 0.f; az[i] = 0.f; ahn[i] = 0.f; ain[i] = 0.f; }
    {
      const bf16x8* pr = g_pk + F_WIH2 + (wc     ) * 1024 + l;
      const bf16x8* pz = g_pk + F_WIH2 + (wc +  8) * 1024 + l;
      const bf16x8* pn = g_pk + F_WIH2 + (wc + 16) * 1024 + l;
#pragma unroll 4
      for (int ks = 0; ks < 16; ++ks) {
        bf16x8 a = *(const bf16x8*)&h1n[am * 256 + (((2 * ks + hv) ^ (am & 31)) << 3)];
        ar  = MFMA(a, pr[ks * 64], ar);
        az  = MFMA(a, pz[ks * 64], az);
        ain = MFMA(a, pn[ks * 64], ain);
      }
    }
    {
      const bf16x8* pr = g_pk + F_WHH2 + (wc     ) * 1024 + l;
      const bf16x8* pz = g_pk + F_WHH2 + (wc +  8) * 1024 + l;
      const bf16x8* pn = g_pk + F_WHH2 + (wc + 16) * 1024 + l;
#pragma unroll 4
      for (int ks = 0; ks < 16; ++ks) {
        bf16x8 a = *(const bf16x8*)&h2c[am * 256 + (((2 * ks + hv) ^ (am & 31)) << 3)];
        ar  = MFMA(a, pr[ks * 64], ar);
        az  = MFMA(a, pz[ks * 64], az);
        ahn = MFMA(a, pn[ks * 64], ahn);
      }
    }
#pragma unroll
    for (int q = 0; q < 16; ++q) {
      float r = sigmoidf_(ar[q] + br2);
      float z = sigmoidf_(az[q] + bz2);
      float n = tanhf_(ain[q] + bi2 + r * (ahn[q] + bh2));
      float h = (1.f - z) * n + z * h2r[q];
      h2r[q]  = h;
      int m = rb + (q & 3) + 8 * (q >> 2) + 4 * hv;
      h2n[m * 256 + (((jd >> 3) ^ (m & 31)) << 3) + (jd & 7)] = bfb(h);
    }
    __syncthreads();

    // ================= output head (wc==0 waves) + next-step x =================
    if (wc == 0) {
      f32x16 ao;
#pragma unroll
      for (int i = 0; i < 16; ++i) ao[i] = 0.f;
      const bf16x8* po = g_pk + F_LIN + l;
#pragma unroll 4
      for (int ks = 0; ks < 16; ++ks) {
        bf16x8 a = *(const bf16x8*)&h2n[am * 256 + (((2 * ks + hv) ^ (am & 31)) << 3)];
        ao = MFMA(a, po[ks * 64], ao);
      }
      if (col < NOUT) {
#pragma unroll
        for (int q = 0; q < 16; ++q) {
          int m   = rb + (q & 3) + 8 * (q >> 2) + 4 * hv;
          float v = ao[q] + lb;
          out[((size_t)(b0 + m) * T + t) * NOUT + col] = v;
          xs[m * 16 + col] = bfb(v);
        }
      }
    }
    if (w == 1 && t + 1 < T) {
      xs[(l << 4) + 5] = bfb(ux);
      xs[(l << 4) + 6] = bfb(uy);
      xs[(l << 4) + 7] = bfb(uz);
    }
    __syncthreads();
    cur ^= 1;
  }
}

extern "C" void kernel_launch(void* const* d_in, const int* in_sizes, int n_in,
                              void* d_out, int out_size, void* d_ws, size_t ws_size,
                              hipStream_t stream) {
  (void)in_sizes; (void)n_in; (void)out_size; (void)d_ws; (void)ws_size;
  const int*   plen  = (const int*)d_in[0];
  const float* rnn   = (const float*)d_in[1];
  const float* out0  = (const float*)d_in[2];
  const float* h01   = (const float*)d_in[3];
  const float* h02   = (const float*)d_in[4];
  const float* wih1  = (const float*)d_in[5];
  const float* whh1  = (const float*)d_in[6];
  const float* bih1  = (const float*)d_in[7];
  const float* bhh1  = (const float*)d_in[8];
  const float* wih2  = (const float*)d_in[9];
  const float* whh2  = (const float*)d_in[10];
  const float* bih2  = (const float*)d_in[11];
  const float* bhh2  = (const float*)d_in[12];
  const float* lin_w = (const float*)d_in[13];
  const float* lin_b = (const float*)d_in[14];

  prepack_kernel<<<(F_TOTAL + 255) / 256, 256, 0, stream>>>(wih1, whh1, wih2, whh2, lin_w);
  gru_kernel<<<NBLK, 1024, 0, stream>>>(plen, rnn, out0, h01, h02,
                                        bih1, bhh1, bih2, bhh2, lin_b,
                                        (float*)d_out);
}